// Round 2
// baseline (336.249 us; speedup 1.0000x reference)
//
#include <hip/hip_runtime.h>
#include <math.h>

// Problem constants (fixed by the reference):
//   z_e: (32, 64, 32, 32) fp32  -> N = 32768 rows of C = 64 (c-stride = 1024 floats)
//   embedding: (1024, 64) fp32
//   outputs flat: z_q_ste (2097152) | loss (1) | indices (32768, as float)
#define NUM_EMB 1024
#define DIM 64
#define WPB 8                      // waves per block
#define CODES_PER_WAVE (NUM_EMB / WPB)   // 128
#define LOSS_OFF 2097152
#define IDX_OFF 2097153

// Emulate numpy's fp32 pairwise sum of 64 contiguous floats on an AVX512
// host (the harness's "ref=np" runs on the MI355X host CPU, Zen4/5):
//   r0..r3 = 16-lane vectors x[0:16],x[16:32],x[32:48],x[48:64]
//   sum    = (r0 + r1) + (r2 + r3)            (lane-wise)
//   result = XOR-fold horizontal sum (8,4,2,1)
// All adds pinned with __fadd_rn (no reassociation / contraction).
// Fallback variants if indices still mismatch:
//   V2: 2-acc AVX512:  lane j = (x[j]+x[j+32]) + (x[j+16]+x[j+48])
//   V3: AVX2 4-acc;  V4: scalar 8-acc stride-8;  V5: full fp64 (fp64-ref hyp.)
__device__ __forceinline__ float np_pairwise_sum64(const float* __restrict__ x) {
    float y[16];
#pragma unroll
    for (int j = 0; j < 16; ++j) {
        float a = __fadd_rn(x[j],      x[j + 16]);
        float b = __fadd_rn(x[j + 32], x[j + 48]);
        y[j] = __fadd_rn(a, b);
    }
#pragma unroll
    for (int j = 0; j < 8; ++j) y[j] = __fadd_rn(y[j], y[j + 8]);
#pragma unroll
    for (int j = 0; j < 4; ++j) y[j] = __fadd_rn(y[j], y[j + 4]);
    y[0] = __fadd_rn(y[0], y[2]);
    y[1] = __fadd_rn(y[1], y[3]);
    return __fadd_rn(y[0], y[1]);
}

// ---- Kernel 0: per-code |e_k|^2 with the SAME numpy summation pattern ----
__global__ void vq_emb_norms(const float* __restrict__ emb,
                             float* __restrict__ norms) {
    int k = blockIdx.x * blockDim.x + threadIdx.x;
    if (k < NUM_EMB) {
        const float* e = emb + k * DIM;
        float x[DIM];
#pragma unroll
        for (int i = 0; i < DIM; ++i) x[i] = __fmul_rn(e[i], e[i]);
        norms[k] = np_pairwise_sum64(x);
    }
}

// ---- Kernel 1: distances (bitwise-numpy fp32) + argmin + STE + loss ----
// Block = 512 threads = 8 waves; block owns 64 rows (lane = row),
// wave w scans codes [w*128, (w+1)*128) in ascending order.
__global__ __launch_bounds__(WPB * 64)
void vq_main(const float* __restrict__ z_e,
             const float* __restrict__ emb,
             const float* __restrict__ norms,
             float* __restrict__ out) {
    __shared__ float s_best[WPB][64];
    __shared__ int   s_idx[WPB][64];
    __shared__ int   s_final[64];

    const int lane = threadIdx.x & 63;
    const int wave = threadIdx.x >> 6;
    const int n0   = blockIdx.x * 64;         // first row of this block
    const int b    = n0 >> 10;                // batch index (H*W = 1024 rows/b)
    const int hw   = (n0 & 1023) + lane;      // h*32 + w for this lane's row
    const long zbase = (long)b * 65536 + hw;  // z_e[b][c][hw] = zbase + c*1024

    // Load this lane's full z row (coalesced 256B per c across the wave).
    float z[DIM];
#pragma unroll
    for (int c = 0; c < DIM; ++c) z[c] = z_e[zbase + (long)c * 1024];

    // A = numpy-bitwise sum(z^2): separate square rounding, then pairwise.
    float A;
    {
        float x[DIM];
#pragma unroll
        for (int c = 0; c < DIM; ++c) x[c] = __fmul_rn(z[c], z[c]);
        A = np_pairwise_sum64(x);
    }

    // Distance scan. emb/norms addresses are wave-uniform -> scalar loads;
    // inner loop is pure v_fma. Reference rounding chain:
    //   t = fl32(A - 2*dot)   [2*dot exact => single fmaf == numpy's subtract]
    //   d = fl32(t + |e_k|^2)
    float best = INFINITY;
    int   bidx = 0;
    const int k0 = wave * CODES_PER_WAVE;
    for (int k = k0; k < k0 + CODES_PER_WAVE; ++k) {
        const float* __restrict__ e = emb + k * DIM;
        float dot = 0.f;
#pragma unroll
        for (int c = 0; c < DIM; ++c) dot = __fmaf_rn(z[c], e[c], dot);
        float t = __fmaf_rn(-2.f, dot, A);
        float d = __fadd_rn(t, norms[k]);
        if (d < best) { best = d; bidx = k; }   // strict <: first-min kept
    }
    s_best[wave][lane] = best;
    s_idx[wave][lane]  = bidx;
    __syncthreads();

    // Combine 8 per-wave candidates in ascending code order (strict <)
    // -> reproduces np.argmin first-occurrence tie-break exactly.
    if (wave == 0) {
        float bb = s_best[0][lane];
        int   bi = s_idx[0][lane];
#pragma unroll
        for (int w = 1; w < WPB; ++w) {
            float v = s_best[w][lane];
            int   i = s_idx[w][lane];
            if (v < bb) { bb = v; bi = i; }
        }
        s_final[lane] = bi;
        out[IDX_OFF + n0 + lane] = (float)bi;   // indices compared as float
    }
    __syncthreads();

    // Write phase: wave w handles c in [w*8, w*8+8) for all 64 rows
    // (lane = row keeps stores coalesced).
    const int fidx = s_final[lane];
    float lsum = 0.f;
#pragma unroll
    for (int j = 0; j < DIM / WPB; ++j) {
        const int c = wave * (DIM / WPB) + j;
        float zc = z_e[zbase + (long)c * 1024];
        float ec = emb[fidx * DIM + c];
        // STE forward: z + (z_q - z), elementwise-identical to the reference
        out[((long)(b * 64 + c)) * 1024 + hw] = zc + (ec - zc);
        float dlt = zc - ec;                    // loss uses z - z_q
        lsum = fmaf(dlt, dlt, lsum);
    }
    // Wave-level butterfly reduce, one atomic per wave.
#pragma unroll
    for (int off = 32; off >= 1; off >>= 1) lsum += __shfl_xor(lsum, off, 64);
    if (lane == 0) {
        // 0.25 / 2097152 = 2^-23 exactly
        atomicAdd(out + LOSS_OFF, lsum * 1.1920928955078125e-07f);
    }
}

extern "C" void kernel_launch(void* const* d_in, const int* in_sizes, int n_in,
                              void* d_out, int out_size, void* d_ws, size_t ws_size,
                              hipStream_t stream) {
    const float* z_e = (const float*)d_in[0];
    const float* emb = (const float*)d_in[1];
    float* out   = (float*)d_out;
    float* norms = (float*)d_ws;   // 1024 floats of scratch

    // Loss accumulator must be zeroed each call (d_out is re-poisoned).
    hipMemsetAsync((char*)d_out + (size_t)LOSS_OFF * sizeof(float), 0,
                   sizeof(float), stream);

    vq_emb_norms<<<dim3(NUM_EMB / 256), dim3(256), 0, stream>>>(emb, norms);
    vq_main<<<dim3(32768 / 64), dim3(WPB * 64), 0, stream>>>(z_e, emb, norms, out);
}

// Round 3
// 187.264 us; speedup vs baseline: 1.7956x; 1.7956x over previous
//
#include <hip/hip_runtime.h>
#include <math.h>

// Problem constants (fixed by the reference):
//   z_e: (32, 64, 32, 32) fp32  -> N = 32768 rows of C = 64 (c-stride = 1024 floats)
//   embedding: (1024, 64) fp32
//   outputs flat: z_q_ste (2097152) | loss (1) | indices (32768, as float)
#define NUM_EMB 1024
#define DIM 64
#define LOSS_OFF 2097152
#define IDX_OFF 2097153

#define SPLITS 4                         // code-range splits across blocks
#define CODES_PER_BLOCK (NUM_EMB / SPLITS)   // 256
#define CHUNK 64                         // codes staged per LDS buffer
#define NCHUNK (CODES_PER_BLOCK / CHUNK) // 4
#define ROW_GROUPS 256                   // 32768 rows / 128 rows per block

typedef __attribute__((address_space(3))) void lds_void_t;
typedef const __attribute__((address_space(1))) void glob_void_t;

// numpy fp32 pairwise tail: fold 16 lanes -> scalar (8,4,2,1 XOR-fold).
// Matches the verified round-2 np_pairwise_sum64 bitwise.
__device__ __forceinline__ float np_fold16(float* y) {
#pragma unroll
    for (int j = 0; j < 8; ++j) y[j] = __fadd_rn(y[j], y[j + 8]);
#pragma unroll
    for (int j = 0; j < 4; ++j) y[j] = __fadd_rn(y[j], y[j + 4]);
    y[0] = __fadd_rn(y[0], y[2]);
    y[1] = __fadd_rn(y[1], y[3]);
    return __fadd_rn(y[0], y[1]);
}

// ---- Kernel 0: per-code |e_k|^2 with the numpy summation pattern ----
__global__ void vq_emb_norms(const float* __restrict__ emb,
                             float* __restrict__ norms) {
    int k = blockIdx.x * blockDim.x + threadIdx.x;
    if (k < NUM_EMB) {
        const float* e = emb + k * DIM;
        float y[16];
#pragma unroll
        for (int j = 0; j < 16; ++j) {
            float a = __fadd_rn(__fmul_rn(e[j],      e[j]),
                                __fmul_rn(e[j + 16], e[j + 16]));
            float b = __fadd_rn(__fmul_rn(e[j + 32], e[j + 32]),
                                __fmul_rn(e[j + 48], e[j + 48]));
            y[j] = __fadd_rn(a, b);
        }
        norms[k] = np_fold16(y);
    }
}

// ---- Kernel 1: distance scan + packed-key argmin ----
// Block = 256 thr = 4 waves. Each lane owns 2 rows (z in 128 VGPRs).
// Block covers 128 rows x 256 codes; e staged in LDS (double-buffered,
// async global_load_lds); waves split each 64-code chunk 4 ways.
// Result per (row, split): u64 key = (f32bits(d) << 32) | k  -> u64-min
// is exactly np.argmin (d > 0 so bits are monotone; ties -> lowest k).
__global__ __launch_bounds__(256, 3)
void vq_dist(const float* __restrict__ z_e,
             const float* __restrict__ emb,
             const float* __restrict__ norms,
             unsigned long long* __restrict__ keys) {
    __shared__ float s_e[2][CHUNK * DIM];          // 32 KB staged codes
    __shared__ float s_E[CODES_PER_BLOCK];         // 1 KB norms slice
    __shared__ unsigned long long s_keys[4 * 128]; // 4 KB wave candidates

    const int tid  = threadIdx.x;
    const int lane = tid & 63;
    const int wave = tid >> 6;
    const int g     = blockIdx.x & (ROW_GROUPS - 1); // row-group 0..255
    const int split = blockIdx.x >> 8;               // code split 0..3
    const int kb    = split * CODES_PER_BLOCK;

    const int b   = g >> 3;
    const int hw0 = ((g & 7) << 7) + lane;           // lane's row-0 h*32+w
    const long zb = (long)b * 65536 + hw0;           // z_e[b][c][hw] = zb + c*1024

    // Load this lane's two z rows into registers (coalesced per c).
    float z0[DIM], z1[DIM];
#pragma unroll
    for (int c = 0; c < DIM; ++c) {
        z0[c] = z_e[zb + (long)c * 1024];
        z1[c] = z_e[zb + 64 + (long)c * 1024];
    }

    // A = numpy-bitwise sum(z^2) per row (fused pairwise, same rounding).
    float A0, A1;
    {
        float y0[16], y1[16];
#pragma unroll
        for (int j = 0; j < 16; ++j) {
            float a0 = __fadd_rn(__fmul_rn(z0[j], z0[j]),
                                 __fmul_rn(z0[j + 16], z0[j + 16]));
            float b0 = __fadd_rn(__fmul_rn(z0[j + 32], z0[j + 32]),
                                 __fmul_rn(z0[j + 48], z0[j + 48]));
            y0[j] = __fadd_rn(a0, b0);
            float a1 = __fadd_rn(__fmul_rn(z1[j], z1[j]),
                                 __fmul_rn(z1[j + 16], z1[j + 16]));
            float b1 = __fadd_rn(__fmul_rn(z1[j + 32], z1[j + 32]),
                                 __fmul_rn(z1[j + 48], z1[j + 48]));
            y1[j] = __fadd_rn(a1, b1);
        }
        A0 = np_fold16(y0);
        A1 = np_fold16(y1);
    }

    // Stage this block's norms slice (256 threads -> 256 codes).
    s_E[tid] = norms[kb + tid];

    // Async stage of one 64-code chunk (16 KB): 256 thr x 4 x 16 B.
    // LDS dst = wave-uniform base + lane*16 per issue -> layout requirement met.
    auto stage = [&](int ch, int buf) {
        const float* gsrc = emb + (size_t)(kb + ch * CHUNK) * DIM;
#pragma unroll
        for (int i = 0; i < 4; ++i) {
#if __has_builtin(__builtin_amdgcn_global_load_lds)
            __builtin_amdgcn_global_load_lds(
                (glob_void_t*)(gsrc + i * 1024 + tid * 4),
                (lds_void_t*)(&s_e[buf][i * 1024 + tid * 4]),
                16, 0, 0);
#else
            float4 t4 = *(const float4*)(gsrc + i * 1024 + tid * 4);
            *(float4*)(&s_e[buf][i * 1024 + tid * 4]) = t4;
#endif
        }
    };

    unsigned long long best0 = ~0ull, best1 = ~0ull;
    stage(0, 0);
    __syncthreads();   // drains stage(0) (barrier implies vmcnt(0)) + s_E visible

    for (int ch = 0; ch < NCHUNK; ++ch) {
        const int buf = ch & 1;
        if (ch + 1 < NCHUNK) stage(ch + 1, buf ^ 1);  // prefetch next chunk

        const int cl0 = ch * CHUNK + wave * 16;       // this wave's 16 codes
        for (int kk = 0; kk < 16; ++kk) {
            const int cl = cl0 + kk;                  // block-local code id
            const float4* e4 = (const float4*)&s_e[buf][(wave * 16 + kk) * DIM];
            // Serial ascending-c dot per row (bitwise == round-2 chain);
            // the two rows are independent chains -> full FMA issue rate.
            float dot0 = 0.f, dot1 = 0.f;
#pragma unroll
            for (int j = 0; j < 16; ++j) {
                float4 ev = e4[j];                    // ds_read_b128, broadcast
                dot0 = __fmaf_rn(z0[4 * j + 0], ev.x, dot0);
                dot1 = __fmaf_rn(z1[4 * j + 0], ev.x, dot1);
                dot0 = __fmaf_rn(z0[4 * j + 1], ev.y, dot0);
                dot1 = __fmaf_rn(z1[4 * j + 1], ev.y, dot1);
                dot0 = __fmaf_rn(z0[4 * j + 2], ev.z, dot0);
                dot1 = __fmaf_rn(z1[4 * j + 2], ev.z, dot1);
                dot0 = __fmaf_rn(z0[4 * j + 3], ev.w, dot0);
                dot1 = __fmaf_rn(z1[4 * j + 3], ev.w, dot1);
            }
            // Reference rounding chain: d = fl(fl(A - 2*dot) + E_k)
            const float E  = s_E[cl];
            const float d0 = __fadd_rn(__fmaf_rn(-2.f, dot0, A0), E);
            const float d1 = __fadd_rn(__fmaf_rn(-2.f, dot1, A1), E);
            const unsigned int k = (unsigned int)(kb + cl);
            const unsigned long long k0 =
                ((unsigned long long)__float_as_uint(d0) << 32) | k;
            const unsigned long long k1 =
                ((unsigned long long)__float_as_uint(d1) << 32) | k;
            if (k0 < best0) best0 = k0;
            if (k1 < best1) best1 = k1;
        }
        __syncthreads();  // compute(ch) done everywhere; stage(ch+1) drained
    }

    // Cross-wave combine: u64 min over the 4 waves, one slot per row.
    s_keys[wave * 128 + lane]      = best0;   // row g*128 + lane
    s_keys[wave * 128 + 64 + lane] = best1;   // row g*128 + 64 + lane
    __syncthreads();
    if (tid < 128) {
        unsigned long long m = s_keys[tid];
        unsigned long long t1 = s_keys[128 + tid]; if (t1 < m) m = t1;
        unsigned long long t2 = s_keys[256 + tid]; if (t2 < m) m = t2;
        unsigned long long t3 = s_keys[384 + tid]; if (t3 < m) m = t3;
        keys[(size_t)(g * 128 + tid) * SPLITS + split] = m;
    }
}

// ---- Kernel 2: pick winners, write indices + z_q_ste + loss ----
// Identical arithmetic to the round-2 write phase (verified).
__global__ __launch_bounds__(512)
void vq_epilogue(const float* __restrict__ z_e,
                 const float* __restrict__ emb,
                 const unsigned long long* __restrict__ keys,
                 float* __restrict__ out) {
    __shared__ int s_final[64];
    const int tid  = threadIdx.x;
    const int lane = tid & 63;
    const int wave = tid >> 6;
    const int n0   = blockIdx.x * 64;

    if (tid < 64) {
        const unsigned long long* kr = keys + (size_t)(n0 + tid) * SPLITS;
        unsigned long long m = kr[0];
        if (kr[1] < m) m = kr[1];
        if (kr[2] < m) m = kr[2];
        if (kr[3] < m) m = kr[3];
        const int k = (int)(m & 0xFFFFFFFFu);
        s_final[tid] = k;
        out[IDX_OFF + n0 + tid] = (float)k;
    }
    __syncthreads();

    const int b  = n0 >> 10;
    const int hw = (n0 & 1023) + lane;
    const long zbase = (long)b * 65536 + hw;
    const int fidx = s_final[lane];
    float lsum = 0.f;
#pragma unroll
    for (int j = 0; j < DIM / 8; ++j) {
        const int c = wave * 8 + j;
        const float zc = z_e[zbase + (long)c * 1024];
        const float ec = emb[fidx * DIM + c];
        out[((long)(b * 64 + c)) * 1024 + hw] = zc + (ec - zc);  // STE forward
        const float dlt = zc - ec;
        lsum = __fmaf_rn(dlt, dlt, lsum);
    }
#pragma unroll
    for (int off = 32; off >= 1; off >>= 1) lsum += __shfl_xor(lsum, off, 64);
    if (lane == 0) {
        // 0.25 / 2097152 = 2^-23 exactly
        atomicAdd(out + LOSS_OFF, lsum * 1.1920928955078125e-07f);
    }
}

extern "C" void kernel_launch(void* const* d_in, const int* in_sizes, int n_in,
                              void* d_out, int out_size, void* d_ws, size_t ws_size,
                              hipStream_t stream) {
    const float* z_e = (const float*)d_in[0];
    const float* emb = (const float*)d_in[1];
    float* out = (float*)d_out;

    float* norms = (float*)d_ws;                                   // 4 KB
    unsigned long long* keys =
        (unsigned long long*)((char*)d_ws + 4096);                 // 1 MB

    // Loss accumulator must be zeroed each call (d_out is re-poisoned).
    hipMemsetAsync((char*)d_out + (size_t)LOSS_OFF * sizeof(float), 0,
                   sizeof(float), stream);

    vq_emb_norms<<<dim3(NUM_EMB / 256), dim3(256), 0, stream>>>(emb, norms);
    vq_dist<<<dim3(ROW_GROUPS * SPLITS), dim3(256), 0, stream>>>(z_e, emb,
                                                                 norms, keys);
    vq_epilogue<<<dim3(32768 / 64), dim3(512), 0, stream>>>(z_e, emb, keys, out);
}

// Round 4
// 149.404 us; speedup vs baseline: 2.2506x; 1.2534x over previous
//
#include <hip/hip_runtime.h>
#include <math.h>
#include <stdint.h>

// Problem constants (fixed by the reference):
//   z_e: (32, 64, 32, 32) fp32  -> N = 32768 rows of C = 64 (c-stride = 1024 floats)
//   embedding: (1024, 64) fp32
//   outputs flat: z_q_ste (2097152) | loss (1) | indices (32768, as float)
#define NUM_EMB 1024
#define DIM 64
#define LOSS_OFF 2097152
#define IDX_OFF 2097153

// Constant-address-space float: uniform-address loads from here compile to
// s_load (scalar cache -> SGPR). SGPR operands in v_fma are FREE (no LDS/VMEM
// broadcast tax: round-3 showed ds_read_b128 broadcasts cost ~8cyc of LDS
// return BW each -> ~55us; SGPR broadcast costs zero vector-memory cycles).
typedef __attribute__((address_space(4))) const float cfloat_t;

// numpy fp32 pairwise tail: fold 16 lanes -> scalar (8,4,2,1 XOR-fold).
// Bitwise-matches the verified round-2/3 np summation.
__device__ __forceinline__ float np_fold16(float* y) {
#pragma unroll
    for (int j = 0; j < 8; ++j) y[j] = __fadd_rn(y[j], y[j + 8]);
#pragma unroll
    for (int j = 0; j < 4; ++j) y[j] = __fadd_rn(y[j], y[j + 4]);
    y[0] = __fadd_rn(y[0], y[2]);
    y[1] = __fadd_rn(y[1], y[3]);
    return __fadd_rn(y[0], y[1]);
}

// ---- Kernel 0: per-code |e_k|^2 with the numpy summation pattern (verified)
__global__ void vq_emb_norms(const float* __restrict__ emb,
                             float* __restrict__ norms) {
    int k = blockIdx.x * blockDim.x + threadIdx.x;
    if (k < NUM_EMB) {
        const float* e = emb + k * DIM;
        float y[16];
#pragma unroll
        for (int j = 0; j < 16; ++j) {
            float a = __fadd_rn(__fmul_rn(e[j],      e[j]),
                                __fmul_rn(e[j + 16], e[j + 16]));
            float b = __fadd_rn(__fmul_rn(e[j + 32], e[j + 32]),
                                __fmul_rn(e[j + 48], e[j + 48]));
            y[j] = __fadd_rn(a, b);
        }
        norms[k] = np_fold16(y);
    }
}

// ---- Fused kernel: distances + argmin + indices + STE + loss ----
// 512 blocks x 512 thr (8 waves). Block owns 64 rows; lane = row (z[64] in
// VGPRs); wave w scans codes [w*128,(w+1)*128) streamed via s_load (SGPR
// operands). Two codes in flight -> two independent FMA chains -> full VALU
// issue rate. Packed u64 key (f32bits(d)<<32 | k): u64-min == np.argmin
// (d>0 -> monotone bits; ties -> lowest k).
__global__ __launch_bounds__(512, 3)
void vq_fused(const float* __restrict__ z_e,
              const float* __restrict__ emb,
              const float* __restrict__ norms,
              float* __restrict__ out) {
    __shared__ unsigned long long s_keys[8 * 64];
    __shared__ int   s_final[64];
    __shared__ float s_loss[8];

    const int tid  = threadIdx.x;
    const int lane = tid & 63;
    const int wave = __builtin_amdgcn_readfirstlane(tid >> 6);  // pin uniform

    const int n0 = blockIdx.x * 64;           // first row of this block
    const int b  = n0 >> 10;                  // batch (H*W = 1024 rows per b)
    const int hw = (n0 & 1023) + lane;        // h*32 + w for this lane's row
    const long zbase = (long)b * 65536 + hw;  // z_e[b][c][hw] = zbase + c*1024

    // Load this lane's z row (coalesced 256B per c; waves 1..7 hit L1).
    float z[DIM];
#pragma unroll
    for (int c = 0; c < DIM; ++c) z[c] = z_e[zbase + (long)c * 1024];

    // A = numpy-bitwise sum(z^2) (verified chain).
    float A;
    {
        float y[16];
#pragma unroll
        for (int j = 0; j < 16; ++j) {
            float a = __fadd_rn(__fmul_rn(z[j],      z[j]),
                                __fmul_rn(z[j + 16], z[j + 16]));
            float c2 = __fadd_rn(__fmul_rn(z[j + 32], z[j + 32]),
                                 __fmul_rn(z[j + 48], z[j + 48]));
            y[j] = __fadd_rn(a, c2);
        }
        A = np_fold16(y);
    }

    // Scalar-path views of the codebook + norms (uniform addresses).
    cfloat_t* E  = (cfloat_t*)(uintptr_t)emb;
    cfloat_t* Nr = (cfloat_t*)(uintptr_t)norms;

    unsigned long long best = ~0ull;
    const int kbase = wave * (NUM_EMB / 8);   // 128 codes per wave, ascending
    for (int kk = 0; kk < NUM_EMB / 8; kk += 2) {
        const int k0 = kbase + kk;
        cfloat_t* e0 = E + (size_t)k0 * DIM;
        cfloat_t* e1 = e0 + DIM;
        // Serial ascending-c fmaf chain per code (bitwise == verified rounds);
        // the two codes are independent chains -> saturate VALU issue.
        float dot0 = 0.f, dot1 = 0.f;
#pragma unroll
        for (int c = 0; c < DIM; ++c) {
            dot0 = __fmaf_rn(z[c], e0[c], dot0);
            dot1 = __fmaf_rn(z[c], e1[c], dot1);
        }
        // Reference rounding chain: d = fl(fl(A - 2*dot) + E_k)
        const float d0 = __fadd_rn(__fmaf_rn(-2.f, dot0, A), Nr[k0]);
        const float d1 = __fadd_rn(__fmaf_rn(-2.f, dot1, A), Nr[k0 + 1]);
        const unsigned long long key0 =
            ((unsigned long long)__float_as_uint(d0) << 32) | (unsigned)k0;
        const unsigned long long key1 =
            ((unsigned long long)__float_as_uint(d1) << 32) | (unsigned)(k0 + 1);
        if (key0 < best) best = key0;
        if (key1 < best) best = key1;
    }
    s_keys[wave * 64 + lane] = best;
    __syncthreads();

    // Per-row u64 min over the 8 waves; write indices.
    if (tid < 64) {
        unsigned long long m = s_keys[tid];
#pragma unroll
        for (int w = 1; w < 8; ++w) {
            unsigned long long t = s_keys[w * 64 + tid];
            if (t < m) m = t;
        }
        const int k = (int)(m & 0xFFFFFFFFu);
        s_final[tid] = k;
        out[IDX_OFF + n0 + tid] = (float)k;   // indices compared as float
    }
    __syncthreads();

    // STE + loss: wave w handles c in [w*8, w*8+8) for all 64 rows
    // (lane = row keeps loads/stores coalesced). Verified round-3 chain.
    const int fidx = s_final[lane];
    float lsum = 0.f;
#pragma unroll
    for (int j = 0; j < DIM / 8; ++j) {
        const int c = wave * 8 + j;
        const float zc = z_e[zbase + (long)c * 1024];   // L1-hot
        const float ec = emb[fidx * DIM + c];           // per-lane gather, L2-hot
        out[((long)(b * 64 + c)) * 1024 + hw] = zc + (ec - zc);  // STE forward
        const float dlt = zc - ec;
        lsum = __fmaf_rn(dlt, dlt, lsum);
    }
#pragma unroll
    for (int off = 32; off >= 1; off >>= 1) lsum += __shfl_xor(lsum, off, 64);
    if (lane == 0) s_loss[wave] = lsum;
    __syncthreads();

    // ONE atomic per block (round 3 had 4096 same-address atomics).
    if (tid == 0) {
        float t = 0.f;
#pragma unroll
        for (int w = 0; w < 8; ++w) t = __fadd_rn(t, s_loss[w]);
        // 0.25 / 2097152 = 2^-23 exactly
        atomicAdd(out + LOSS_OFF, t * 1.1920928955078125e-07f);
    }
}

extern "C" void kernel_launch(void* const* d_in, const int* in_sizes, int n_in,
                              void* d_out, int out_size, void* d_ws, size_t ws_size,
                              hipStream_t stream) {
    const float* z_e = (const float*)d_in[0];
    const float* emb = (const float*)d_in[1];
    float* out   = (float*)d_out;
    float* norms = (float*)d_ws;   // 4 KB scratch

    // Loss accumulator must be zeroed each call (d_out is re-poisoned).
    hipMemsetAsync((char*)d_out + (size_t)LOSS_OFF * sizeof(float), 0,
                   sizeof(float), stream);

    vq_emb_norms<<<dim3(NUM_EMB / 256), dim3(256), 0, stream>>>(emb, norms);
    vq_fused<<<dim3(32768 / 64), dim3(512), 0, stream>>>(z_e, emb, norms, out);
}

// Round 5
// 149.166 us; speedup vs baseline: 2.2542x; 1.0016x over previous
//
#include <hip/hip_runtime.h>
#include <math.h>
#include <stdint.h>

// Problem constants (fixed by the reference):
//   z_e: (32, 64, 32, 32) fp32  -> N = 32768 rows of C = 64 (c-stride = 1024 floats)
//   embedding: (1024, 64) fp32
//   outputs flat: z_q_ste (2097152) | loss (1) | indices (32768, as float)
#define NUM_EMB 1024
#define DIM 64
#define LOSS_OFF 2097152
#define IDX_OFF 2097153

// Constant-address-space float: uniform-address loads compile to s_load
// (scalar cache -> SGPR). SGPR operands in v_fma are free of the vector-memory
// broadcast tax (r3 measured: ds_read_b128 broadcast ~12cyc of LDS return BW
// each -> ~80us/CU; SGPR broadcast costs zero vector-memory cycles).
typedef __attribute__((address_space(4))) const float cfloat_t;

// numpy fp32 pairwise tail: fold 16 lanes -> scalar (8,4,2,1 XOR-fold).
// Bitwise-matches the verified round-2/3/4 np summation.
__device__ __forceinline__ float np_fold16(float* y) {
#pragma unroll
    for (int j = 0; j < 8; ++j) y[j] = __fadd_rn(y[j], y[j + 8]);
#pragma unroll
    for (int j = 0; j < 4; ++j) y[j] = __fadd_rn(y[j], y[j + 4]);
    y[0] = __fadd_rn(y[0], y[2]);
    y[1] = __fadd_rn(y[1], y[3]);
    return __fadd_rn(y[0], y[1]);
}

// ---- Kernel 0: per-code |e_k|^2 with the numpy summation pattern (verified)
__global__ void vq_emb_norms(const float* __restrict__ emb,
                             float* __restrict__ norms) {
    int k = blockIdx.x * blockDim.x + threadIdx.x;
    if (k < NUM_EMB) {
        const float* e = emb + k * DIM;
        float y[16];
#pragma unroll
        for (int j = 0; j < 16; ++j) {
            float a = __fadd_rn(__fmul_rn(e[j],      e[j]),
                                __fmul_rn(e[j + 16], e[j + 16]));
            float b = __fadd_rn(__fmul_rn(e[j + 32], e[j + 32]),
                                __fmul_rn(e[j + 48], e[j + 48]));
            y[j] = __fadd_rn(a, b);
        }
        norms[k] = np_fold16(y);
    }
}

// ---- Fused kernel: distances + argmin + indices + STE + loss ----
// 512 blocks x 512 thr (8 waves). Block owns 64 rows; lane = row (z[64]
// PINNED in VGPRs via asm barrier); wave w scans codes [w*128,(w+1)*128)
// streamed via s_load (SGPR operands). Two codes in flight -> two
// independent FMA chains. Packed u64 key (f32bits(d)<<32 | k): u64-min ==
// np.argmin (d>0 -> monotone bits; ties -> lowest k).
// __launch_bounds__(512,4): 4 waves/EU -> VGPR cap 128 (z=64 + ~25 misc fits),
// 2 blocks/CU for scalar-latency hiding.
__global__ __launch_bounds__(512, 4)
void vq_fused(const float* __restrict__ z_e,
              const float* __restrict__ emb,
              const float* __restrict__ norms,
              float* __restrict__ out) {
    __shared__ unsigned long long s_keys[8 * 64];
    __shared__ int   s_final[64];
    __shared__ float s_loss[8];

    const int tid  = threadIdx.x;
    const int lane = tid & 63;
    const int wave = __builtin_amdgcn_readfirstlane(tid >> 6);  // pin uniform

    const int n0 = blockIdx.x * 64;           // first row of this block
    const int b  = n0 >> 10;                  // batch (H*W = 1024 rows per b)
    const int hw = (n0 & 1023) + lane;        // h*32 + w for this lane's row
    const long zbase = (long)b * 65536 + hw;  // z_e[b][c][hw] = zbase + c*1024

    // Load this lane's z row (coalesced 256B per c; waves 1..7 hit L1).
    float z[DIM];
#pragma unroll
    for (int c = 0; c < DIM; ++c) z[c] = z_e[zbase + (long)c * 1024];

    // PIN z in VGPRs. r3/r4 post-mortem: without this the compiler sinks the
    // z loads into the code loop (r4: VGPR_Count=44!) and pays ~2x VALU in
    // per-iteration reload+addressing. Empty asm is an identity with an
    // opaque result: loads can't be sunk or rematerialized. Zero numerics
    // change -> correctness inherited from verified rounds.
#pragma unroll
    for (int c = 0; c < DIM; ++c) asm volatile("" : "+v"(z[c]));

    // A = numpy-bitwise sum(z^2) (verified chain).
    float A;
    {
        float y[16];
#pragma unroll
        for (int j = 0; j < 16; ++j) {
            float a = __fadd_rn(__fmul_rn(z[j],      z[j]),
                                __fmul_rn(z[j + 16], z[j + 16]));
            float c2 = __fadd_rn(__fmul_rn(z[j + 32], z[j + 32]),
                                 __fmul_rn(z[j + 48], z[j + 48]));
            y[j] = __fadd_rn(a, c2);
        }
        A = np_fold16(y);
    }

    // Scalar-path views of the codebook + norms (uniform addresses).
    cfloat_t* E  = (cfloat_t*)(uintptr_t)emb;
    cfloat_t* Nr = (cfloat_t*)(uintptr_t)norms;

    unsigned long long best = ~0ull;
    const int kbase = wave * (NUM_EMB / 8);   // 128 codes per wave, ascending
    for (int kk = 0; kk < NUM_EMB / 8; kk += 2) {
        const int k0 = kbase + kk;
        cfloat_t* e0 = E + (size_t)k0 * DIM;
        cfloat_t* e1 = e0 + DIM;
        // Serial ascending-c fmaf chain per code (bitwise == verified rounds);
        // the two codes are independent chains -> saturate VALU issue.
        float dot0 = 0.f, dot1 = 0.f;
#pragma unroll
        for (int c = 0; c < DIM; ++c) {
            dot0 = __fmaf_rn(z[c], e0[c], dot0);
            dot1 = __fmaf_rn(z[c], e1[c], dot1);
        }
        // Reference rounding chain: d = fl(fl(A - 2*dot) + E_k)
        const float d0 = __fadd_rn(__fmaf_rn(-2.f, dot0, A), Nr[k0]);
        const float d1 = __fadd_rn(__fmaf_rn(-2.f, dot1, A), Nr[k0 + 1]);
        const unsigned long long key0 =
            ((unsigned long long)__float_as_uint(d0) << 32) | (unsigned)k0;
        const unsigned long long key1 =
            ((unsigned long long)__float_as_uint(d1) << 32) | (unsigned)(k0 + 1);
        if (key0 < best) best = key0;
        if (key1 < best) best = key1;
    }
    s_keys[wave * 64 + lane] = best;
    __syncthreads();

    // Per-row u64 min over the 8 waves; write indices.
    if (tid < 64) {
        unsigned long long m = s_keys[tid];
#pragma unroll
        for (int w = 1; w < 8; ++w) {
            unsigned long long t = s_keys[w * 64 + tid];
            if (t < m) m = t;
        }
        const int k = (int)(m & 0xFFFFFFFFu);
        s_final[tid] = k;
        out[IDX_OFF + n0 + tid] = (float)k;   // indices compared as float
    }
    __syncthreads();

    // STE + loss: wave w handles c in [w*8, w*8+8) for all 64 rows
    // (lane = row keeps loads/stores coalesced). Verified round-3/4 chain.
    const int fidx = s_final[lane];
    float lsum = 0.f;
#pragma unroll
    for (int j = 0; j < DIM / 8; ++j) {
        const int c = wave * 8 + j;
        const float zc = z_e[zbase + (long)c * 1024];   // L1-hot
        const float ec = emb[fidx * DIM + c];           // per-lane gather, L2-hot
        out[((long)(b * 64 + c)) * 1024 + hw] = zc + (ec - zc);  // STE forward
        const float dlt = zc - ec;
        lsum = __fmaf_rn(dlt, dlt, lsum);
    }
#pragma unroll
    for (int off = 32; off >= 1; off >>= 1) lsum += __shfl_xor(lsum, off, 64);
    if (lane == 0) s_loss[wave] = lsum;
    __syncthreads();

    // ONE atomic per block.
    if (tid == 0) {
        float t = 0.f;
#pragma unroll
        for (int w = 0; w < 8; ++w) t = __fadd_rn(t, s_loss[w]);
        // 0.25 / 2097152 = 2^-23 exactly
        atomicAdd(out + LOSS_OFF, t * 1.1920928955078125e-07f);
    }
}

extern "C" void kernel_launch(void* const* d_in, const int* in_sizes, int n_in,
                              void* d_out, int out_size, void* d_ws, size_t ws_size,
                              hipStream_t stream) {
    const float* z_e = (const float*)d_in[0];
    const float* emb = (const float*)d_in[1];
    float* out   = (float*)d_out;
    float* norms = (float*)d_ws;   // 4 KB scratch

    // Loss accumulator must be zeroed each call (d_out is re-poisoned).
    hipMemsetAsync((char*)d_out + (size_t)LOSS_OFF * sizeof(float), 0,
                   sizeof(float), stream);

    vq_emb_norms<<<dim3(NUM_EMB / 256), dim3(256), 0, stream>>>(emb, norms);
    vq_fused<<<dim3(32768 / 64), dim3(512), 0, stream>>>(z_e, emb, norms, out);
}